// Round 3
// baseline (1034.303 us; speedup 1.0000x reference)
//
#include <hip/hip_runtime.h>
#include <hip/hip_bf16.h>

#define NT 8192      // tokens
#define DM 1024      // d_model
#define NE 8         // experts
#define DH 4096      // d_hidden
#define NP (NT * 2)  // token-expert pairs (TOP_K = 2)

typedef __attribute__((ext_vector_type(8))) __bf16 bf16x8;
typedef __attribute__((ext_vector_type(4))) float f32x4;

__device__ __forceinline__ ushort f2bf(float f) {
  unsigned int x = __float_as_uint(f);
  unsigned int r = (x + 0x7fffu + ((x >> 16) & 1u)) >> 16;  // RNE
  return (ushort)r;
}

__device__ __forceinline__ float gelu_tanh(float x) {
  float u = 0.7978845608028654f * (x + 0.044715f * x * x * x);
  float t = 1.0f - 2.0f / (__expf(2.0f * u) + 1.0f);
  return 0.5f * x * (1.0f + t);
}

__device__ __forceinline__ void async_copy16(const void* gsrc, void* ldst) {
  __builtin_amdgcn_global_load_lds(
      (const __attribute__((address_space(1))) void*)gsrc,
      (__attribute__((address_space(3))) void*)ldst, 16, 0, 0);
}

// ---------------- input -> bf16 ----------------
__global__ void cvt_inp_kernel(const float* __restrict__ in, ushort* __restrict__ out) {
  size_t i = ((size_t)blockIdx.x * blockDim.x + threadIdx.x) * 4;
  float4 v = *(const float4*)(in + i);
  ushort4 o;
  o.x = f2bf(v.x); o.y = f2bf(v.y); o.z = f2bf(v.z); o.w = f2bf(v.w);
  *(ushort4*)(out + i) = o;
}

// ------------- transpose + convert: in [E][R][C] f32 -> out [E][C][R] bf16 -------------
__global__ void transpose_cvt_kernel(const float* __restrict__ in, ushort* __restrict__ out,
                                     int R, int C) {
  __shared__ float tile[32][33];
  int e = blockIdx.z;
  const float* src = in + (size_t)e * R * C;
  ushort* dst = out + (size_t)e * R * C;
  int c0 = blockIdx.x * 32, r0 = blockIdx.y * 32;
  int tx = threadIdx.x & 31, ty = threadIdx.x >> 5;  // 32 x 8
  for (int i = ty; i < 32; i += 8)
    tile[i][tx] = src[(size_t)(r0 + i) * C + c0 + tx];
  __syncthreads();
  for (int i = ty; i < 32; i += 8)
    dst[(size_t)(c0 + i) * R + r0 + tx] = f2bf(tile[tx][i]);
}

// ---------------- gating: logits -> top2 -> softmax -> routing lists ----------------
__global__ void gate_kernel(const float* __restrict__ inp, const float* __restrict__ gw,
                            const float* __restrict__ gb, int* __restrict__ counts,
                            int* __restrict__ tok_list, float* __restrict__ scale_list) {
  int wave = threadIdx.x >> 6, lane = threadIdx.x & 63;
  int token = blockIdx.x * 4 + wave;
  const float* x = inp + (size_t)token * DM;
  float acc[NE];
#pragma unroll
  for (int e = 0; e < NE; e++) acc[e] = 0.f;
  int base = lane * 16;
#pragma unroll
  for (int j = 0; j < 16; j++) {
    float xv = x[base + j];
#pragma unroll
    for (int e = 0; e < NE; e++) acc[e] += xv * gw[(base + j) * NE + e];
  }
#pragma unroll
  for (int e = 0; e < NE; e++) {
    for (int off = 32; off; off >>= 1) acc[e] += __shfl_xor(acc[e], off, 64);
  }
  if (lane == 0) {
    float v[NE];
#pragma unroll
    for (int e = 0; e < NE; e++) v[e] = acc[e] + gb[e];
    int i0 = 0; float b0 = v[0];
#pragma unroll
    for (int e = 1; e < NE; e++) if (v[e] > b0) { b0 = v[e]; i0 = e; }
    int i1 = -1; float b1v = -INFINITY;
#pragma unroll
    for (int e = 0; e < NE; e++) if (e != i0 && v[e] > b1v) { b1v = v[e]; i1 = e; }
    float s1 = 1.f / (1.f + __expf(b0 - b1v));  // softmax over the two selected logits
    float s0 = 1.f - s1;
    int p0 = atomicAdd(&counts[i0], 1);
    tok_list[i0 * NT + p0] = token;
    scale_list[i0 * NT + p0] = s0;
    int p1 = atomicAdd(&counts[i1], 1);
    tok_list[i1 * NT + p1] = token;
    scale_list[i1 * NT + p1] = s1;
  }
}

// ---------------- GEMM1: h[off_e+gi] = gelu(x[tok] @ w1[e] + b1[e]), bf16 dense ----------------
// XCD swizzle: 1D grid, e = b&7 (pins each expert to one XCD under round-robin
// linear%8 mapping), mTile fastest so A (token rows, ~4MB/expert) stays L2-resident
// per nTile sweep and each B slice is fetched once.
__global__ __launch_bounds__(256) void gemm1_kernel(
    const ushort* __restrict__ xbf, const ushort* __restrict__ w1t,
    const float* __restrict__ b1, const int* __restrict__ tok_list,
    const int* __restrict__ counts, ushort* __restrict__ hbuf) {
  const int b = blockIdx.x;
  const int e = b & 7;
  const int idx = b >> 3;        // 0..2047
  const int mTile = idx & 63;    // fastest
  const int nTile = idx >> 6;    // 0..31
  int off = 0;
  for (int i = 0; i < e; i++) off += counts[i];
  const int cnt = counts[e];
  if (mTile * 128 >= cnt) return;

  __shared__ ushort lds[8192];  // A: 128x32, B(T): 128x32
  ushort* As = lds;
  ushort* Bs = lds + 4096;

  const int t = threadIdx.x;
  const int lane = t & 63, wv = t >> 6;
  const int wm = wv & 1, wn = wv >> 1;

  const int sr = t >> 2;
  const int sc = (t & 3) * 8;
  int gi0 = mTile * 128 + sr;      if (gi0 >= cnt) gi0 = cnt - 1;
  int gi1 = mTile * 128 + 64 + sr; if (gi1 >= cnt) gi1 = cnt - 1;
  const int tok0 = tok_list[e * NT + gi0];
  const int tok1 = tok_list[e * NT + gi1];
  const ushort* aP0 = xbf + (size_t)tok0 * DM + sc;
  const ushort* aP1 = xbf + (size_t)tok1 * DM + sc;
  const ushort* bP0 = w1t + ((size_t)e * DH + nTile * 128 + sr) * DM + sc;
  const ushort* bP1 = bP0 + (size_t)64 * DM;

  f32x4 zero = {0.f, 0.f, 0.f, 0.f};
  f32x4 acc[4][4];
#pragma unroll
  for (int i = 0; i < 4; i++)
#pragma unroll
    for (int j = 0; j < 4; j++) acc[i][j] = zero;

  const int quad = lane >> 4, lc = lane & 15;

  for (int k0 = 0; k0 < DM; k0 += 32) {
    __syncthreads();
    async_copy16(aP0, (char*)As + wv * 1024);
    async_copy16(aP1, (char*)As + 4096 + wv * 1024);
    async_copy16(bP0, (char*)Bs + wv * 1024);
    async_copy16(bP1, (char*)Bs + 4096 + wv * 1024);
    aP0 += 32; aP1 += 32; bP0 += 32; bP1 += 32;
    __syncthreads();
    bf16x8 af[4], bfr[4];
#pragma unroll
    for (int mi = 0; mi < 4; mi++) {
      int row = wm * 64 + mi * 16 + lc;
      af[mi] = *(const bf16x8*)((const char*)As + row * 64 + quad * 16);
    }
#pragma unroll
    for (int ni = 0; ni < 4; ni++) {
      int row = wn * 64 + ni * 16 + lc;
      bfr[ni] = *(const bf16x8*)((const char*)Bs + row * 64 + quad * 16);
    }
#pragma unroll
    for (int mi = 0; mi < 4; mi++)
#pragma unroll
      for (int ni = 0; ni < 4; ni++)
        acc[mi][ni] = __builtin_amdgcn_mfma_f32_16x16x32_bf16(af[mi], bfr[ni], acc[mi][ni], 0, 0, 0);
  }

  float bias[4];
#pragma unroll
  for (int ni = 0; ni < 4; ni++)
    bias[ni] = b1[(size_t)e * DH + nTile * 128 + wn * 64 + ni * 16 + lc];

#pragma unroll
  for (int mi = 0; mi < 4; mi++) {
#pragma unroll
    for (int r = 0; r < 4; r++) {
      int lr = wm * 64 + mi * 16 + quad * 4 + r;
      int gi = mTile * 128 + lr;
      if (gi < cnt) {
        ushort* hrow = hbuf + (size_t)(off + gi) * DH + nTile * 128 + wn * 64 + lc;
#pragma unroll
        for (int ni = 0; ni < 4; ni++) {
          float v = acc[mi][ni][r] + bias[ni];
          hrow[ni * 16] = f2bf(gelu_tanh(v));
        }
      }
    }
  }
}

// ---------------- GEMM2 (split-K x2): y[tok] += scale * (h @ w2[e] + b2[e]) ----------------
// XCD swizzle: e = b&7 pins expert to XCD; B panel per expert-split = 4MB = one L2.
// nTile fastest: each A tile consumed by 8 consecutive same-XCD blocks.
__global__ __launch_bounds__(256) void gemm2_kernel(
    const ushort* __restrict__ hbuf, const ushort* __restrict__ w2t,
    const float* __restrict__ b2, const int* __restrict__ tok_list,
    const float* __restrict__ scale_list, const int* __restrict__ counts,
    float* __restrict__ y) {
  const int b = blockIdx.x;
  const int ks = b >> 12;            // split-K index: 0 or 1 (grid halves)
  const int e = b & 7;               // XCD pin
  const int idx = (b >> 3) & 511;
  const int nTile = idx & 7;         // fastest
  const int mTile = idx >> 3;        // 0..63
  int off = 0;
  for (int i = 0; i < e; i++) off += counts[i];
  const int cnt = counts[e];
  if (mTile * 128 >= cnt) return;

  __shared__ ushort lds[8192];
  ushort* As = lds;
  ushort* Bs = lds + 4096;

  const int t = threadIdx.x;
  const int lane = t & 63, wv = t >> 6;
  const int wm = wv & 1, wn = wv >> 1;

  const int sr = t >> 2;
  const int sc = (t & 3) * 8;
  int gi0 = mTile * 128 + sr;      if (gi0 >= cnt) gi0 = cnt - 1;
  int gi1 = mTile * 128 + 64 + sr; if (gi1 >= cnt) gi1 = cnt - 1;
  const int kBase = ks * (DH / 2);
  const ushort* aP0 = hbuf + (size_t)(off + gi0) * DH + kBase + sc;
  const ushort* aP1 = hbuf + (size_t)(off + gi1) * DH + kBase + sc;
  const ushort* bP0 = w2t + ((size_t)e * DM + nTile * 128 + sr) * DH + kBase + sc;
  const ushort* bP1 = bP0 + (size_t)64 * DH;

  f32x4 zero = {0.f, 0.f, 0.f, 0.f};
  f32x4 acc[4][4];
#pragma unroll
  for (int i = 0; i < 4; i++)
#pragma unroll
    for (int j = 0; j < 4; j++) acc[i][j] = zero;

  const int quad = lane >> 4, lc = lane & 15;

  for (int k0 = 0; k0 < DH / 2; k0 += 32) {
    __syncthreads();
    async_copy16(aP0, (char*)As + wv * 1024);
    async_copy16(aP1, (char*)As + 4096 + wv * 1024);
    async_copy16(bP0, (char*)Bs + wv * 1024);
    async_copy16(bP1, (char*)Bs + 4096 + wv * 1024);
    aP0 += 32; aP1 += 32; bP0 += 32; bP1 += 32;
    __syncthreads();
    bf16x8 af[4], bfr[4];
#pragma unroll
    for (int mi = 0; mi < 4; mi++) {
      int row = wm * 64 + mi * 16 + lc;
      af[mi] = *(const bf16x8*)((const char*)As + row * 64 + quad * 16);
    }
#pragma unroll
    for (int ni = 0; ni < 4; ni++) {
      int row = wn * 64 + ni * 16 + lc;
      bfr[ni] = *(const bf16x8*)((const char*)Bs + row * 64 + quad * 16);
    }
#pragma unroll
    for (int mi = 0; mi < 4; mi++)
#pragma unroll
      for (int ni = 0; ni < 4; ni++)
        acc[mi][ni] = __builtin_amdgcn_mfma_f32_16x16x32_bf16(af[mi], bfr[ni], acc[mi][ni], 0, 0, 0);
  }

  float bias[4];
#pragma unroll
  for (int ni = 0; ni < 4; ni++)
    bias[ni] = (ks == 0) ? b2[(size_t)e * DM + nTile * 128 + wn * 64 + ni * 16 + lc] : 0.f;

#pragma unroll
  for (int mi = 0; mi < 4; mi++) {
#pragma unroll
    for (int r = 0; r < 4; r++) {
      int lr = wm * 64 + mi * 16 + quad * 4 + r;
      int gi = mTile * 128 + lr;
      if (gi < cnt) {
        int tok = tok_list[e * NT + gi];
        float s = scale_list[e * NT + gi];
        float* yrow = y + (size_t)tok * DM + nTile * 128 + wn * 64 + lc;
#pragma unroll
        for (int ni = 0; ni < 4; ni++) {
          float v = (acc[mi][ni][r] + bias[ni]) * s;
          unsafeAtomicAdd(&yrow[ni * 16], v);
        }
      }
    }
  }
}

extern "C" void kernel_launch(void* const* d_in, const int* in_sizes, int n_in,
                              void* d_out, int out_size, void* d_ws, size_t ws_size,
                              hipStream_t stream) {
  const float* inp = (const float*)d_in[0];
  const float* gw  = (const float*)d_in[1];
  const float* gb  = (const float*)d_in[2];
  const float* w1  = (const float*)d_in[3];
  const float* b1  = (const float*)d_in[4];
  const float* w2  = (const float*)d_in[5];
  const float* b2  = (const float*)d_in[6];
  float* y = (float*)d_out;

  // workspace layout (~286 MB total)
  char* ws = (char*)d_ws;
  ushort* inp_bf = (ushort*)ws;              ws += (size_t)NT * DM * 2;
  ushort* w1t    = (ushort*)ws;              ws += (size_t)NE * DH * DM * 2;
  ushort* w2t    = (ushort*)ws;              ws += (size_t)NE * DM * DH * 2;
  ushort* hbuf   = (ushort*)ws;              ws += (size_t)NP * DH * 2;
  int*    tok_list   = (int*)ws;             ws += (size_t)NE * NT * 4;
  float*  scale_list = (float*)ws;           ws += (size_t)NE * NT * 4;
  int*    counts     = (int*)ws;             ws += 256;

  hipMemsetAsync(counts, 0, 256, stream);
  hipMemsetAsync(d_out, 0, (size_t)out_size * sizeof(float), stream);

  cvt_inp_kernel<<<(NT * DM) / (256 * 4), 256, 0, stream>>>(inp, inp_bf);
  // w1 [E][DM][DH] -> w1t [E][DH][DM]
  transpose_cvt_kernel<<<dim3(DH / 32, DM / 32, NE), 256, 0, stream>>>(w1, w1t, DM, DH);
  // w2 [E][DH][DM] -> w2t [E][DM][DH]
  transpose_cvt_kernel<<<dim3(DM / 32, DH / 32, NE), 256, 0, stream>>>(w2, w2t, DH, DM);
  gate_kernel<<<NT / 4, 256, 0, stream>>>(inp, gw, gb, counts, tok_list, scale_list);
  // 1D swizzled grids: XCD = linear%8 = expert
  gemm1_kernel<<<NE * 32 * 64, 256, 0, stream>>>(inp_bf, w1t, b1, tok_list, counts, hbuf);
  gemm2_kernel<<<2 * NE * 8 * 64, 256, 0, stream>>>(hbuf, w2t, b2, tok_list, scale_list, counts, y);
}

// Round 4
// 985.331 us; speedup vs baseline: 1.0497x; 1.0497x over previous
//
#include <hip/hip_runtime.h>
#include <hip/hip_bf16.h>

#define NT 8192      // tokens
#define DM 1024      // d_model
#define NE 8         // experts
#define DH 4096      // d_hidden
#define NP (NT * 2)  // token-expert pairs (TOP_K = 2)

typedef __attribute__((ext_vector_type(8))) __bf16 bf16x8;
typedef __attribute__((ext_vector_type(4))) float f32x4;

__device__ __forceinline__ ushort f2bf(float f) {
  unsigned int x = __float_as_uint(f);
  unsigned int r = (x + 0x7fffu + ((x >> 16) & 1u)) >> 16;  // RNE
  return (ushort)r;
}

// exact tanh-gelu, rearranged: 0.5x(1+tanh(z)) = x*e^{2z}/(e^{2z}+1),
// exponent = 2*0.7978845608*log2(e)*u = 2.3025851*u, u = x+0.044715x^3
__device__ __forceinline__ float gelu_fast(float x) {
  float x2 = x * x;
  float t = __builtin_fmaf(x2, 0.044715f, 1.0f);
  float m = x * t * 2.3025851f;
  m = fminf(m, 126.0f);                      // avoid inf/inf
  float p = __builtin_amdgcn_exp2f(m);
  return x * p * __builtin_amdgcn_rcpf(p + 1.0f);
}

__device__ __forceinline__ void async_copy16(const void* gsrc, void* ldst) {
  __builtin_amdgcn_global_load_lds(
      (const __attribute__((address_space(1))) void*)gsrc,
      (__attribute__((address_space(3))) void*)ldst, 16, 0, 0);
}

// ------------- fused weight transpose+cvt: w1 [E][DM][DH] -> w1t [E][DH][DM],
//               w2 [E][DH][DM] -> w2t [E][DM][DH]. 64x64 tiles, 256 thr. -------------
__global__ __launch_bounds__(256) void transpose2_kernel(
    const float* __restrict__ w1, const float* __restrict__ w2,
    ushort* __restrict__ w1t, ushort* __restrict__ w2t) {
  const int b = blockIdx.x;
  const int which = b >> 13;         // 0 = w1, 1 = w2
  const int rem = b & 8191;
  const int e = rem >> 10;
  const int t = rem & 1023;          // 1024 tiles of 64x64 per expert-weight
  const float* src;
  ushort* dst;
  int R, C, c0, r0;
  if (which == 0) {
    src = w1 + (size_t)e * DM * DH; dst = w1t + (size_t)e * DM * DH;
    R = DM; C = DH; c0 = (t & 63) * 64; r0 = (t >> 6) * 64;
  } else {
    src = w2 + (size_t)e * DM * DH; dst = w2t + (size_t)e * DM * DH;
    R = DH; C = DM; c0 = (t & 15) * 64; r0 = (t >> 4) * 64;
  }
  __shared__ ushort tileT[64][72];   // [col][row], stride 72: 2-way bank alias only, 8B-aligned rows
  const int tx = threadIdx.x & 15, ty = threadIdx.x >> 4;  // 16 x 16
#pragma unroll
  for (int i = 0; i < 4; i++) {
    int r = ty + i * 16;
    float4 v = *(const float4*)(src + (size_t)(r0 + r) * C + c0 + tx * 4);
    tileT[tx * 4 + 0][r] = f2bf(v.x);
    tileT[tx * 4 + 1][r] = f2bf(v.y);
    tileT[tx * 4 + 2][r] = f2bf(v.z);
    tileT[tx * 4 + 3][r] = f2bf(v.w);
  }
  __syncthreads();
#pragma unroll
  for (int i = 0; i < 4; i++) {
    int c = ty + i * 16;
    *(ushort4*)(dst + (size_t)(c0 + c) * R + r0 + tx * 4) = *(const ushort4*)(&tileT[c][tx * 4]);
  }
}

// ---------------- gating (+ fused input->bf16): one wave per token ----------------
__global__ void gate_cvt_kernel(const float* __restrict__ inp, const float* __restrict__ gw,
                                const float* __restrict__ gb, ushort* __restrict__ inp_bf,
                                int* __restrict__ counts, int* __restrict__ tok_list,
                                float* __restrict__ scale_list) {
  int wave = threadIdx.x >> 6, lane = threadIdx.x & 63;
  int token = blockIdx.x * 4 + wave;
  const float* x = inp + (size_t)token * DM;
  ushort* xb = inp_bf + (size_t)token * DM;
  float acc[NE];
#pragma unroll
  for (int e = 0; e < NE; e++) acc[e] = 0.f;
#pragma unroll
  for (int j = 0; j < 16; j++) {
    int idx = j * 64 + lane;
    float xv = x[idx];
    xb[idx] = f2bf(xv);
    const float4* g = (const float4*)(gw + (size_t)idx * NE);
    float4 g0 = g[0], g1 = g[1];
    acc[0] += xv * g0.x; acc[1] += xv * g0.y; acc[2] += xv * g0.z; acc[3] += xv * g0.w;
    acc[4] += xv * g1.x; acc[5] += xv * g1.y; acc[6] += xv * g1.z; acc[7] += xv * g1.w;
  }
#pragma unroll
  for (int e = 0; e < NE; e++) {
    for (int off = 32; off; off >>= 1) acc[e] += __shfl_xor(acc[e], off, 64);
  }
  if (lane == 0) {
    float v[NE];
#pragma unroll
    for (int e = 0; e < NE; e++) v[e] = acc[e] + gb[e];
    int i0 = 0; float b0 = v[0];
#pragma unroll
    for (int e = 1; e < NE; e++) if (v[e] > b0) { b0 = v[e]; i0 = e; }
    int i1 = -1; float b1v = -INFINITY;
#pragma unroll
    for (int e = 0; e < NE; e++) if (e != i0 && v[e] > b1v) { b1v = v[e]; i1 = e; }
    float s1 = 1.f / (1.f + __expf(b0 - b1v));  // softmax over the two selected logits
    float s0 = 1.f - s1;
    int p0 = atomicAdd(&counts[i0], 1);
    tok_list[i0 * NT + p0] = token;
    scale_list[i0 * NT + p0] = s0;
    int p1 = atomicAdd(&counts[i1], 1);
    tok_list[i1 * NT + p1] = token;
    scale_list[i1 * NT + p1] = s1;
  }
}

// ---------------- GEMM1: h[off_e+gi] = gelu(x[tok] @ w1[e] + b1[e]), bf16 dense ----------------
// XCD swizzle: e = b&7 pins expert to XCD; mTile fastest so A stays L2-resident.
__global__ __launch_bounds__(256) void gemm1_kernel(
    const ushort* __restrict__ xbf, const ushort* __restrict__ w1t,
    const float* __restrict__ b1, const int* __restrict__ tok_list,
    const int* __restrict__ counts, ushort* __restrict__ hbuf) {
  const int b = blockIdx.x;
  const int e = b & 7;
  const int idx = b >> 3;        // 0..2047
  const int mTile = idx & 63;    // fastest
  const int nTile = idx >> 6;    // 0..31
  int off = 0;
  for (int i = 0; i < e; i++) off += counts[i];
  const int cnt = counts[e];
  if (mTile * 128 >= cnt) return;

  __shared__ ushort lds[8192];  // A: 128x32, B(T): 128x32
  ushort* As = lds;
  ushort* Bs = lds + 4096;

  const int t = threadIdx.x;
  const int lane = t & 63, wv = t >> 6;
  const int wm = wv & 1, wn = wv >> 1;

  const int sr = t >> 2;
  const int sc = (t & 3) * 8;
  int gi0 = mTile * 128 + sr;      if (gi0 >= cnt) gi0 = cnt - 1;
  int gi1 = mTile * 128 + 64 + sr; if (gi1 >= cnt) gi1 = cnt - 1;
  const int tok0 = tok_list[e * NT + gi0];
  const int tok1 = tok_list[e * NT + gi1];
  const ushort* aP0 = xbf + (size_t)tok0 * DM + sc;
  const ushort* aP1 = xbf + (size_t)tok1 * DM + sc;
  const ushort* bP0 = w1t + ((size_t)e * DH + nTile * 128 + sr) * DM + sc;
  const ushort* bP1 = bP0 + (size_t)64 * DM;

  f32x4 zero = {0.f, 0.f, 0.f, 0.f};
  f32x4 acc[4][4];
#pragma unroll
  for (int i = 0; i < 4; i++)
#pragma unroll
    for (int j = 0; j < 4; j++) acc[i][j] = zero;

  const int quad = lane >> 4, lc = lane & 15;

  for (int k0 = 0; k0 < DM; k0 += 32) {
    __syncthreads();
    async_copy16(aP0, (char*)As + wv * 1024);
    async_copy16(aP1, (char*)As + 4096 + wv * 1024);
    async_copy16(bP0, (char*)Bs + wv * 1024);
    async_copy16(bP1, (char*)Bs + 4096 + wv * 1024);
    aP0 += 32; aP1 += 32; bP0 += 32; bP1 += 32;
    __syncthreads();
    bf16x8 af[4], bfr[4];
#pragma unroll
    for (int mi = 0; mi < 4; mi++) {
      int row = wm * 64 + mi * 16 + lc;
      af[mi] = *(const bf16x8*)((const char*)As + row * 64 + quad * 16);
    }
#pragma unroll
    for (int ni = 0; ni < 4; ni++) {
      int row = wn * 64 + ni * 16 + lc;
      bfr[ni] = *(const bf16x8*)((const char*)Bs + row * 64 + quad * 16);
    }
#pragma unroll
    for (int mi = 0; mi < 4; mi++)
#pragma unroll
      for (int ni = 0; ni < 4; ni++)
        acc[mi][ni] = __builtin_amdgcn_mfma_f32_16x16x32_bf16(af[mi], bfr[ni], acc[mi][ni], 0, 0, 0);
  }

  float bias[4];
#pragma unroll
  for (int ni = 0; ni < 4; ni++)
    bias[ni] = b1[(size_t)e * DH + nTile * 128 + wn * 64 + ni * 16 + lc];

#pragma unroll
  for (int mi = 0; mi < 4; mi++) {
#pragma unroll
    for (int r = 0; r < 4; r++) {
      int lr = wm * 64 + mi * 16 + quad * 4 + r;
      int gi = mTile * 128 + lr;
      if (gi < cnt) {
        ushort* hrow = hbuf + (size_t)(off + gi) * DH + nTile * 128 + wn * 64 + lc;
#pragma unroll
        for (int ni = 0; ni < 4; ni++) {
          float v = acc[mi][ni][r] + bias[ni];
          hrow[ni * 16] = f2bf(gelu_fast(v));
        }
      }
    }
  }
}

// ---------------- GEMM2 (split-K x2): y[tok] += scale * (h @ w2[e] + b2[e]) ----------------
// XCD swizzle: e = b&7 pins expert to XCD; nTile fastest.
__global__ __launch_bounds__(256) void gemm2_kernel(
    const ushort* __restrict__ hbuf, const ushort* __restrict__ w2t,
    const float* __restrict__ b2, const int* __restrict__ tok_list,
    const float* __restrict__ scale_list, const int* __restrict__ counts,
    float* __restrict__ y) {
  const int b = blockIdx.x;
  const int ks = b >> 12;            // split-K index: 0 or 1 (grid halves)
  const int e = b & 7;               // XCD pin
  const int idx = (b >> 3) & 511;
  const int nTile = idx & 7;         // fastest
  const int mTile = idx >> 3;        // 0..63
  int off = 0;
  for (int i = 0; i < e; i++) off += counts[i];
  const int cnt = counts[e];
  if (mTile * 128 >= cnt) return;

  __shared__ ushort lds[8192];
  ushort* As = lds;
  ushort* Bs = lds + 4096;

  const int t = threadIdx.x;
  const int lane = t & 63, wv = t >> 6;
  const int wm = wv & 1, wn = wv >> 1;

  const int sr = t >> 2;
  const int sc = (t & 3) * 8;
  int gi0 = mTile * 128 + sr;      if (gi0 >= cnt) gi0 = cnt - 1;
  int gi1 = mTile * 128 + 64 + sr; if (gi1 >= cnt) gi1 = cnt - 1;
  const int kBase = ks * (DH / 2);
  const ushort* aP0 = hbuf + (size_t)(off + gi0) * DH + kBase + sc;
  const ushort* aP1 = hbuf + (size_t)(off + gi1) * DH + kBase + sc;
  const ushort* bP0 = w2t + ((size_t)e * DM + nTile * 128 + sr) * DH + kBase + sc;
  const ushort* bP1 = bP0 + (size_t)64 * DH;

  f32x4 zero = {0.f, 0.f, 0.f, 0.f};
  f32x4 acc[4][4];
#pragma unroll
  for (int i = 0; i < 4; i++)
#pragma unroll
    for (int j = 0; j < 4; j++) acc[i][j] = zero;

  const int quad = lane >> 4, lc = lane & 15;

  for (int k0 = 0; k0 < DH / 2; k0 += 32) {
    __syncthreads();
    async_copy16(aP0, (char*)As + wv * 1024);
    async_copy16(aP1, (char*)As + 4096 + wv * 1024);
    async_copy16(bP0, (char*)Bs + wv * 1024);
    async_copy16(bP1, (char*)Bs + 4096 + wv * 1024);
    aP0 += 32; aP1 += 32; bP0 += 32; bP1 += 32;
    __syncthreads();
    bf16x8 af[4], bfr[4];
#pragma unroll
    for (int mi = 0; mi < 4; mi++) {
      int row = wm * 64 + mi * 16 + lc;
      af[mi] = *(const bf16x8*)((const char*)As + row * 64 + quad * 16);
    }
#pragma unroll
    for (int ni = 0; ni < 4; ni++) {
      int row = wn * 64 + ni * 16 + lc;
      bfr[ni] = *(const bf16x8*)((const char*)Bs + row * 64 + quad * 16);
    }
#pragma unroll
    for (int mi = 0; mi < 4; mi++)
#pragma unroll
      for (int ni = 0; ni < 4; ni++)
        acc[mi][ni] = __builtin_amdgcn_mfma_f32_16x16x32_bf16(af[mi], bfr[ni], acc[mi][ni], 0, 0, 0);
  }

  float bias[4];
#pragma unroll
  for (int ni = 0; ni < 4; ni++)
    bias[ni] = (ks == 0) ? b2[(size_t)e * DM + nTile * 128 + wn * 64 + ni * 16 + lc] : 0.f;

#pragma unroll
  for (int mi = 0; mi < 4; mi++) {
#pragma unroll
    for (int r = 0; r < 4; r++) {
      int lr = wm * 64 + mi * 16 + quad * 4 + r;
      int gi = mTile * 128 + lr;
      if (gi < cnt) {
        int tok = tok_list[e * NT + gi];
        float s = scale_list[e * NT + gi];
        float* yrow = y + (size_t)tok * DM + nTile * 128 + wn * 64 + lc;
#pragma unroll
        for (int ni = 0; ni < 4; ni++) {
          float v = (acc[mi][ni][r] + bias[ni]) * s;
          unsafeAtomicAdd(&yrow[ni * 16], v);
        }
      }
    }
  }
}

extern "C" void kernel_launch(void* const* d_in, const int* in_sizes, int n_in,
                              void* d_out, int out_size, void* d_ws, size_t ws_size,
                              hipStream_t stream) {
  const float* inp = (const float*)d_in[0];
  const float* gw  = (const float*)d_in[1];
  const float* gb  = (const float*)d_in[2];
  const float* w1  = (const float*)d_in[3];
  const float* b1  = (const float*)d_in[4];
  const float* w2  = (const float*)d_in[5];
  const float* b2  = (const float*)d_in[6];
  float* y = (float*)d_out;

  // workspace layout (~286 MB total)
  char* ws = (char*)d_ws;
  ushort* inp_bf = (ushort*)ws;              ws += (size_t)NT * DM * 2;
  ushort* w1t    = (ushort*)ws;              ws += (size_t)NE * DH * DM * 2;
  ushort* w2t    = (ushort*)ws;              ws += (size_t)NE * DM * DH * 2;
  ushort* hbuf   = (ushort*)ws;              ws += (size_t)NP * DH * 2;
  int*    tok_list   = (int*)ws;             ws += (size_t)NE * NT * 4;
  float*  scale_list = (float*)ws;           ws += (size_t)NE * NT * 4;
  int*    counts     = (int*)ws;             ws += 256;

  hipMemsetAsync(counts, 0, 256, stream);
  hipMemsetAsync(d_out, 0, (size_t)out_size * sizeof(float), stream);

  transpose2_kernel<<<2 * NE * 1024, 256, 0, stream>>>(w1, w2, w1t, w2t);
  gate_cvt_kernel<<<NT / 4, 256, 0, stream>>>(inp, gw, gb, inp_bf, counts, tok_list, scale_list);
  // 1D swizzled grids: XCD = linear%8 = expert
  gemm1_kernel<<<NE * 32 * 64, 256, 0, stream>>>(inp_bf, w1t, b1, tok_list, counts, hbuf);
  gemm2_kernel<<<2 * NE * 8 * 64, 256, 0, stream>>>(hbuf, w2t, b2, tok_list, scale_list, counts, y);
}